// Round 11
// baseline (29.615 us; speedup 1.0000x reference)
//
#include <hip/hip_runtime.h>
#include <math.h>

// ---------------------------------------------------------------------------
// Z_exp = Tr(M rho^x4) = degree-4 poly in Bloch (x,y,z), 35 monomials.
// R10 post-mortem: chain (~18us) invariant to phase count, code size, ILP,
// and parked-wave TLP. Untested lever: ACTIVE chain waves per SIMD.
// R11: 2 redundant chain copies per block (512 thr, separate LDS buffers,
// verbatim R10 phase arithmetic) x 2 blocks/CU = 4 active chain waves/SIMD.
// Eval fused after the last barrier (input float4 prefetched pre-chain).
// ---------------------------------------------------------------------------

struct cpx { float re, im; };

__device__ __forceinline__ cpx cmul(cpx a, cpx b) {
    return { a.re * b.re - a.im * b.im, a.re * b.im + a.im * b.re };
}

// ---- compile-time Pauli-string -> monomial grouping (data-independent) ----
struct MonoTab { unsigned char cnt[125]; unsigned char idx[125][24]; };

constexpr int mono_of(int p) {
    int a = 0, b = 0, c = 0;
    for (int k = 0; k < 4; ++k) {
        const int pk = (p >> (2 * k)) & 3;   // 0=I,1=X,2=Y,3=Z
        a += (pk == 1); b += (pk == 2); c += (pk == 3);
    }
    return (a * 5 + b) * 5 + c;
}
constexpr MonoTab build_tab() {
    MonoTab t{};
    for (int m = 0; m < 125; ++m) {
        t.cnt[m] = 0;
        for (int k = 0; k < 24; ++k) t.idx[m][k] = 0;
    }
    for (int p = 0; p < 256; ++p) {          // ascending p: fixed sum order
        const int m = mono_of(p);
        t.idx[m][t.cnt[m]++] = (unsigned char)p;
    }
    return t;
}
__constant__ const MonoTab TAB = build_tab();

__global__ __launch_bounds__(512) void fused_kernel(
    const float4* __restrict__ in4, const float* __restrict__ w_U,
    const float* __restrict__ w_RXZX, const float* __restrict__ scale_p,
    const float* __restrict__ bias_p, float2* __restrict__ out2, int B2)
{
    // shared (identical across copies)
    __shared__ cpx   R[24][2][2];
    __shared__ float ISc[6], ISs[6];
    __shared__ float cf[125];
    // per-copy chain state (2 redundant copies)
    __shared__ cpx   L[2][6][16][16];
    __shared__ cpx   P1[2][3][16][16];
    __shared__ cpx   Dm[2][16][16];
    __shared__ cpx   Wf[2][16][16];
    __shared__ cpx   Mm[2][16][16];
    __shared__ float cp[2][256];

    const int tid = threadIdx.x;
    const int idx = blockIdx.x * 512 + tid;
    const int cc = tid >> 8;          // copy index 0/1
    const int ct = tid & 255;         // thread within copy
    const int i = ct >> 4, j = ct & 15;

    // prefetch batch data (4 VGPR); latency hidden under the chain
    float4 f = make_float4(0.f, 0.f, 0.f, 0.f);
    if (idx < B2) f = in4[idx];

    // ---- Phase 1: gates (copy 0 only; shared read-only afterwards) ----
    if (tid < 24) {
        const float ta = w_RXZX[tid * 3 + 0];
        const float tb = w_RXZX[tid * 3 + 1];
        const float tc = w_RXZX[tid * 3 + 2];
        float sa, ca, sb, cb, sc, cc2;
        sincosf(0.5f * ta, &sa, &ca);
        sincosf(0.5f * tb, &sb, &cb);
        sincosf(0.5f * tc, &sc, &cc2);
        // RX(t)=[[c,-is],[-is,c]], RZ(t)=diag(c-is,c+is); g = RX(a)RZ(b)RX(c)
        const cpx e0 = { cb, -sb };
        const cpx e1 = { cb,  sb };
        const cpx T00 = { e0.re * cc2, e0.im * cc2 };
        const cpx T01 = { -e0.im * (-sc), e0.re * (-sc) };
        const cpx T10 = { -e1.im * (-sc), e1.re * (-sc) };
        const cpx T11 = { e1.re * cc2, e1.im * cc2 };
        R[tid][0][0] = { ca * T00.re + sa * T10.im, ca * T00.im - sa * T10.re };
        R[tid][0][1] = { ca * T01.re + sa * T11.im, ca * T01.im - sa * T11.re };
        R[tid][1][0] = { sa * T00.im + ca * T10.re, -sa * T00.re + ca * T10.im };
        R[tid][1][1] = { sa * T01.im + ca * T11.re, -sa * T01.re + ca * T11.im };
    } else if (tid < 30) {
        const int l = tid - 24;
        float s, c;
        sincosf(w_U[l], &s, &c);
        ISc[l] = c;
        ISs[l] = s;
    }
    __syncthreads();

    // ---- Phase 2: L[cc][l] = (GA on iSWAP pair) x (GB on complement) ----
    // PAIR byte per layer l: qa | qb<<2 | qr<<4 | qs<<6,
    // PAIRS=[(1,2),(1,3),(1,2),(1,3),(0,3),(0,2)]
    for (int l = 0; l < 6; ++l) {
        const int code = (int)((0xD89C8DC98DC9ULL >> (8 * l)) & 0xFF);
        const int qa = code & 3, qb = (code >> 2) & 3;
        const int qr = (code >> 4) & 3, qs = (code >> 6) & 3;
        const int uAi = (((i >> (3 - qa)) & 1) << 1) | ((i >> (3 - qb)) & 1);
        const int uAj = (((j >> (3 - qa)) & 1) << 1) | ((j >> (3 - qb)) & 1);
        const int uBi = (((i >> (3 - qr)) & 1) << 1) | ((i >> (3 - qs)) & 1);
        const int uBj = (((j >> (3 - qr)) & 1) << 1) | ((j >> (3 - qs)) & 1);
        const int ra = l * 4 + qa, rb = l * 4 + qb;
        cpx ga;
        if (uAj == 0)      ga = cmul(R[ra][uAi >> 1][0], R[rb][uAi & 1][0]);
        else if (uAj == 3) ga = cmul(R[ra][uAi >> 1][1], R[rb][uAi & 1][1]);
        else {
            const cpx k1 = cmul(R[ra][uAi >> 1][0], R[rb][uAi & 1][1]);
            const cpx k2 = cmul(R[ra][uAi >> 1][1], R[rb][uAi & 1][0]);
            const cpx tc = (uAj == 1) ? k1 : k2;   // * cos
            const cpx ts = (uAj == 1) ? k2 : k1;   // * i sin
            const float c = ISc[l], s = ISs[l];
            ga.re = c * tc.re - s * ts.im;
            ga.im = c * tc.im + s * ts.re;
        }
        const cpx gb = cmul(R[l * 4 + qr][uBi >> 1][uBj >> 1],
                            R[l * 4 + qs][uBi & 1][uBj & 1]);
        L[cc][l][i][j] = cmul(ga, gb);
    }
    __syncthreads();

    // ---- Phase 3: P1[m]=L[2m+1]*L[2m], 3 matmuls interleaved ----
    {
        cpx a0 = {0.f, 0.f}, a1 = {0.f, 0.f}, a2 = {0.f, 0.f};
        #pragma unroll 4
        for (int k = 0; k < 16; ++k) {
            const cpx u1 = L[cc][1][i][k], v0 = L[cc][0][k][j];
            const cpx u3 = L[cc][3][i][k], v2 = L[cc][2][k][j];
            const cpx u5 = L[cc][5][i][k], v4 = L[cc][4][k][j];
            a0.re += u1.re * v0.re - u1.im * v0.im;
            a0.im += u1.re * v0.im + u1.im * v0.re;
            a1.re += u3.re * v2.re - u3.im * v2.im;
            a1.im += u3.re * v2.im + u3.im * v2.re;
            a2.re += u5.re * v4.re - u5.im * v4.im;
            a2.im += u5.re * v4.im + u5.im * v4.re;
        }
        P1[cc][0][i][j] = a0; P1[cc][1][i][j] = a1; P1[cc][2][i][j] = a2;
    }
    __syncthreads();

    // ---- Phase 4: D = P1[1]*P1[0], 2-acc k-split ----
    {
        cpx s0 = {0.f, 0.f}, s1 = {0.f, 0.f};
        #pragma unroll 4
        for (int k = 0; k < 8; ++k) {
            const cpx a = P1[cc][1][i][k],     b = P1[cc][0][k][j];
            const cpx c = P1[cc][1][i][k + 8], d = P1[cc][0][k + 8][j];
            s0.re += a.re * b.re - a.im * b.im;
            s0.im += a.re * b.im + a.im * b.re;
            s1.re += c.re * d.re - c.im * d.im;
            s1.im += c.re * d.im + c.im * d.re;
        }
        Dm[cc][i][j] = { s0.re + s1.re, s0.im + s1.im };
    }
    __syncthreads();

    // ---- Phase 5: W = P1[2]*D ----
    {
        cpx s0 = {0.f, 0.f}, s1 = {0.f, 0.f};
        #pragma unroll 4
        for (int k = 0; k < 8; ++k) {
            const cpx a = P1[cc][2][i][k],     b = Dm[cc][k][j];
            const cpx c = P1[cc][2][i][k + 8], d = Dm[cc][k + 8][j];
            s0.re += a.re * b.re - a.im * b.im;
            s0.im += a.re * b.im + a.im * b.re;
            s1.re += c.re * d.re - c.im * d.im;
            s1.im += c.re * d.im + c.im * d.re;
        }
        Wf[cc][i][j] = { s0.re + s1.re, s0.im + s1.im };
    }
    __syncthreads();

    // ---- Phase 6: M[i][j] = sum_k zk conj(W[k][i]) W[k][j] ----
    {
        cpx s0 = {0.f, 0.f}, s1 = {0.f, 0.f};
        #pragma unroll 4
        for (int k = 0; k < 8; ++k) {
            const cpx a = Wf[cc][k][i],     b = Wf[cc][k][j];       // zk=+1
            const cpx c = Wf[cc][k + 8][i], d = Wf[cc][k + 8][j];   // zk=-1
            s0.re += a.re * b.re + a.im * b.im;
            s0.im += a.re * b.im - a.im * b.re;
            s1.re += c.re * d.re + c.im * d.im;
            s1.im += c.re * d.im - c.im * d.re;
        }
        Mm[cc][i][j] = { s0.re - s1.re, s0.im - s1.im };
    }
    __syncthreads();

    // ---- Phase 7: Pauli traces cp[p] = Tr(M*P_p)/16, p = ct ----
    {
        const int p = ct;
        float accre = 0.f;
        #pragma unroll 4
        for (int col = 0; col < 16; ++col) {
            int row = 0;
            cpx val = {1.f, 0.f};
            #pragma unroll
            for (int k = 0; k < 4; ++k) {
                const int pk = (p >> (6 - 2 * k)) & 3;
                const int b = (col >> (3 - k)) & 1;
                int rb = b;
                if (pk == 1) {
                    rb = b ^ 1;
                } else if (pk == 2) {
                    rb = b ^ 1;
                    const cpx fc = {0.f, b ? -1.f : 1.f};
                    val = cmul(val, fc);
                } else if (pk == 3) {
                    if (b) { val.re = -val.re; val.im = -val.im; }
                }
                row |= rb << (3 - k);
            }
            const cpx mv = Mm[cc][col][row];
            accre += mv.re * val.re - mv.im * val.im;
        }
        cp[cc][p] = accre * (1.f / 16.f);
    }
    __syncthreads();

    // ---- Phase 8: collapse (copy 0 only; copies are bit-identical) ----
    if (tid < 125) {
        const int cnt = TAB.cnt[tid];
        float s = 0.f;
        for (int k = 0; k < cnt; ++k)          // ascending: deterministic
            s += cp[0][TAB.idx[tid][k]];
        cf[tid] = s;
    }
    __syncthreads();

    // ---- eval: 2 elements per thread from LDS coefficients ----
    if (idx >= B2) return;
    const float scale = scale_p[0], bias = bias_p[0];

    float2 res;
    #pragma unroll
    for (int e = 0; e < 2; ++e) {
        const float f0 = e ? f.z : f.x;
        const float f1 = e ? f.w : f.y;
        float s0, c0, s1, c1;
        sincosf(f0, &s0, &c0);
        sincosf(f1, &s1, &c1);
        const float x = s1 * c0, y = s1 * s0, z = c1;

        float xp[5], yp[5], zp[5];
        xp[0] = yp[0] = zp[0] = 1.f;
        #pragma unroll
        for (int k = 1; k < 5; ++k) {
            xp[k] = xp[k - 1] * x;
            yp[k] = yp[k - 1] * y;
            zp[k] = zp[k - 1] * z;
        }

        float Z = 0.f;
        #pragma unroll
        for (int a = 0; a <= 4; ++a)
            #pragma unroll
            for (int b = 0; b <= 4 - a; ++b)
                #pragma unroll
                for (int c = 0; c <= 4 - a - b; ++c)
                    Z = fmaf(cf[(a * 5 + b) * 5 + c], xp[a] * yp[b] * zp[c], Z);

        const float noise = 0.04472135954999579f * (Z * Z - 1.f) * 0.25f;
        const float v = scale * (Z + noise) + bias;
        if (e) res.y = v; else res.x = v;
    }
    out2[idx] = res;
}

extern "C" void kernel_launch(void* const* d_in, const int* in_sizes, int n_in,
                              void* d_out, int out_size, void* d_ws, size_t ws_size,
                              hipStream_t stream) {
    const float* inputs  = (const float*)d_in[0];   // [B,2] f32
    const float* w_U     = (const float*)d_in[1];   // [6]
    const float* w_RXZX  = (const float*)d_in[2];   // [6,4,3]
    const float* scale_p = (const float*)d_in[3];   // [1]
    const float* bias_p  = (const float*)d_in[4];   // [1]
    float* out = (float*)d_out;

    const int B  = in_sizes[0] / 2;                 // elements
    const int B2 = B / 2;                           // float4 units (2 el/thread)

    fused_kernel<<<(B2 + 511) / 512, 512, 0, stream>>>(
        (const float4*)inputs, w_U, w_RXZX, scale_p, bias_p, (float2*)out, B2);
}